// Round 4
// baseline (281.118 us; speedup 1.0000x reference)
//
#include <hip/hip_runtime.h>

#define S_DIM 512
#define H_DIM 512
#define NH 256
#define TI 16
#define TJ 8

#define AS1 __attribute__((address_space(1)))
#define AS3 __attribute__((address_space(3)))

typedef _Float16 half8 __attribute__((ext_vector_type(8)));
typedef _Float16 half4 __attribute__((ext_vector_type(4)));
typedef float f32x4 __attribute__((ext_vector_type(4)));

__device__ __forceinline__ int swz(int r) { return ((r & 1) << 2) | (r >> 1); }  // perm of 0..7

// ---------------- k0: fused converts ----------------
__global__ __launch_bounds__(256) void convert_all_kernel(const float* __restrict__ feats,
        const float* __restrict__ W1, const float* __restrict__ W2,
        _Float16* __restrict__ f16, _Float16* __restrict__ w1L, _Float16* __restrict__ w2L) {
    int blk = blockIdx.x;
    if (blk < 512) {
        int t = blk * 256 + threadIdx.x;
        float4 v = ((const float4*)feats)[t];
        half4 h;
        h.x = (_Float16)v.x; h.y = (_Float16)v.y; h.z = (_Float16)v.z; h.w = (_Float16)v.w;
        ((half4*)f16)[t] = h;
    } else if (blk < 768) {
        int t = (blk - 512) * 256 + threadIdx.x;   // 65536
        int gcb = t >> 10, n = t & 1023;
        const float* src = (n < H_DIM) ? &W1[(size_t)(gcb * 8) * H_DIM + n]
                                       : &W1[(size_t)(H_DIM + gcb * 8) * H_DIM + (n - H_DIM)];
        half8 v;
#pragma unroll
        for (int j = 0; j < 8; j++) v[j] = (_Float16)src[(size_t)j * H_DIM];
        *(half8*)&w1L[((size_t)gcb * 1024 + n) * 8] = v;
    } else {
        int t = (blk - 768) * 256 + threadIdx.x;   // 16384
        int gcb = t >> 8, n = t & 255;
        half8 v;
#pragma unroll
        for (int j = 0; j < 8; j++) v[j] = (_Float16)W2[(size_t)(gcb * 8 + j) * NH + n];
        *(half8*)&w2L[((size_t)gcb * 256 + n) * 8] = v;
    }
}

// ---------------- k1: prep GEMM [1024 x 512] @ [512 x 1024], 32x64 tiles ----------
__global__ __launch_bounds__(256) void prep_mfma_kernel(const _Float16* __restrict__ f16,
        const _Float16* __restrict__ w1L, const float* __restrict__ b1,
        _Float16* __restrict__ aH, _Float16* __restrict__ cH) {
    const int n0 = blockIdx.x * 64, m0 = blockIdx.y * 32;
    const int tid = threadIdx.x, wave = tid >> 6, lane = tid & 63;
    const int quad = lane >> 4, l16 = lane & 15;
    const int mg = wave >> 1, ng = wave & 1;
    const int mrow = m0 + mg * 16 + l16;
    int ncol[2];
#pragma unroll
    for (int nt = 0; nt < 2; nt++) ncol[nt] = n0 + ng * 32 + nt * 16 + l16;
    f32x4 acc[2];
    acc[0] = (f32x4)0.f; acc[1] = (f32x4)0.f;
#pragma unroll
    for (int ks = 0; ks < 16; ks++) {
        int gcb = ks * 4 + quad;
        half8 af = *(const half8*)&f16[(size_t)mrow * H_DIM + gcb * 8];
        half8 bf[2];
#pragma unroll
        for (int nt = 0; nt < 2; nt++)
            bf[nt] = *(const half8*)&w1L[((size_t)gcb * 1024 + ncol[nt]) * 8];
#pragma unroll
        for (int nt = 0; nt < 2; nt++)
            acc[nt] = __builtin_amdgcn_mfma_f32_16x16x32_f16(af, bf[nt], acc[nt], 0, 0, 0);
    }
    const bool first_half = (n0 < H_DIM);
#pragma unroll
    for (int nt = 0; nt < 2; nt++) {
        float bias = first_half ? b1[ncol[nt]] : 0.f;
#pragma unroll
        for (int r = 0; r < 4; r++) {
            int m = m0 + mg * 16 + quad * 4 + r;
            float v = acc[nt][r] + bias;
            if (first_half) aH[(size_t)m * H_DIM + ncol[nt]] = (_Float16)v;
            else            cH[(size_t)m * H_DIM + (ncol[nt] - H_DIM)] = (_Float16)v;
        }
    }
}

// ---------------- k2: pair GEMM ----------------------------------------------------
// grid (64,32,B). block 512 = 8 waves = 4 M-groups x 2 N-groups.
// Wave tile 32M x 128N (mt=2, nt=8). Block tile = 128 pairs (16i x 8j) x 256N.
__global__ __launch_bounds__(512, 4) void pair_kernel(
        const _Float16* __restrict__ aH, const _Float16* __restrict__ cH,
        const _Float16* __restrict__ w2L,
        const float* __restrict__ b2, const float* __restrict__ W3,
        const float* __restrict__ b3, float* __restrict__ out) {
    const int jt = blockIdx.x, it = blockIdx.y, b = blockIdx.z;
    const int i0 = it * TI, j0 = jt * TJ;

    __shared__ __align__(16) _Float16 sa[TI * H_DIM];   // 16 KB
    __shared__ __align__(16) _Float16 sc[TJ * H_DIM];   //  8 KB
    __shared__ float spart[2][128];                     //  1 KB

    const int tid = threadIdx.x;
    const int wave = tid >> 6, lane = tid & 63;
    const int quad = lane >> 4, l16 = lane & 15;
    const int mg = wave >> 1, ng = wave & 1;
    const int nb = ng * 128;

    // ---- stage 16 a-rows + 8 c-rows, swizzled (LDS slot s of row r <- chunk s^swz(r&7))
#pragma unroll
    for (int rr0 = 0; rr0 < 3; rr0++) {
        int rr = rr0 * 8 + wave;
        int gc = lane ^ swz(rr & 7);
        if (rr < TI) {
            __builtin_amdgcn_global_load_lds(
                (const AS1 unsigned int*)&aH[((size_t)(b * S_DIM + i0 + rr)) * H_DIM + gc * 8],
                (AS3 unsigned int*)&sa[rr * H_DIM], 16, 0, 0);
        } else {
            int cr = rr - TI;
            __builtin_amdgcn_global_load_lds(
                (const AS1 unsigned int*)&cH[((size_t)(b * S_DIM + j0 + cr)) * H_DIM + gc * 8],
                (AS3 unsigned int*)&sc[cr * H_DIM], 16, 0, 0);
        }
    }

    // pair row r = mg*32 + mt*16 + l16 ; il = r>>3, jl = r&7
    int saoff[2], swzA[2];
#pragma unroll
    for (int mt = 0; mt < 2; mt++) {
        int il = mg * 4 + mt * 2 + (l16 >> 3);
        saoff[mt] = il * H_DIM;
        swzA[mt] = swz(il & 7);
    }
    const int jl = l16 & 7;
    const int scoff = jl * H_DIM, swzC = swz(jl);

    f32x4 acc[2][8];
#pragma unroll
    for (int mt = 0; mt < 2; mt++)
#pragma unroll
        for (int nt = 0; nt < 8; nt++) acc[mt][nt] = (f32x4)0.f;

    // B: fragment-major w2L, chunk (gcb, n) at (gcb*256+n)*16B. Walk +16KB per ks.
    const _Float16* bp = &w2L[((size_t)quad * 256 + nb + l16) * 8];
    half8 bnxt[8];
#pragma unroll
    for (int nt = 0; nt < 8; nt++) bnxt[nt] = *(const half8*)&bp[nt * 16 * 8];

    __syncthreads();   // sa/sc staged

#pragma unroll
    for (int ks = 0; ks < 16; ks++) {
        half8 bf[8];
#pragma unroll
        for (int nt = 0; nt < 8; nt++) bf[nt] = bnxt[nt];
        if (ks < 15) {
            const _Float16* bn = bp + (size_t)4 * 256 * 8;
#pragma unroll
            for (int nt = 0; nt < 8; nt++) bnxt[nt] = *(const half8*)&bn[nt * 16 * 8];
            bp = bn;
        }
        const int gcb = ks * 4 + quad;
        half8 vc = *(const half8*)&sc[scoff + (gcb ^ swzC) * 8];
        half8 af[2];
#pragma unroll
        for (int mt = 0; mt < 2; mt++) {
            half8 va = *(const half8*)&sa[saoff[mt] + (gcb ^ swzA[mt]) * 8];
            af[mt] = __builtin_elementwise_max(va + vc, (half8)(_Float16)0.f);
        }
#pragma unroll
        for (int nt = 0; nt < 8; nt++)
#pragma unroll
            for (int mt = 0; mt < 2; mt++)
                acc[mt][nt] = __builtin_amdgcn_mfma_f32_16x16x32_f16(af[mt], bf[nt],
                                                                     acc[mt][nt], 0, 0, 0);
    }

    // ---- fused epilogue ----
    float b2v[8], w3v[8];
#pragma unroll
    for (int nt = 0; nt < 8; nt++) {
        int n = nb + nt * 16 + l16;
        b2v[nt] = b2[n];
        w3v[nt] = W3[n];
    }
    float ps[2][4];
#pragma unroll
    for (int mt = 0; mt < 2; mt++)
#pragma unroll
        for (int r = 0; r < 4; r++) {
            float s = 0.f;
#pragma unroll
            for (int nt = 0; nt < 8; nt++) {
                float v = acc[mt][nt][r] + b2v[nt];
                v = v > 0.f ? v : 0.f;
                s += v * w3v[nt];
            }
            ps[mt][r] = s;
        }
#pragma unroll
    for (int mt = 0; mt < 2; mt++)
#pragma unroll
        for (int r = 0; r < 4; r++) {
            float s = ps[mt][r];
            s += __shfl_xor(s, 8, 16);
            s += __shfl_xor(s, 4, 16);
            s += __shfl_xor(s, 2, 16);
            s += __shfl_xor(s, 1, 16);
            ps[mt][r] = s;
        }
    if (l16 == 0) {
#pragma unroll
        for (int mt = 0; mt < 2; mt++)
#pragma unroll
            for (int r = 0; r < 4; r++)
                spart[ng][mg * 32 + mt * 16 + quad * 4 + r] = ps[mt][r];
    }
    __syncthreads();
    if (tid < 128) {
        float tot = spart[0][tid] + spart[1][tid] + b3[0];
        float sg = 1.f / (1.f + __expf(-tot));
        int i = i0 + (tid >> 3), j = j0 + (tid & 7);
        out[(size_t)b * S_DIM * S_DIM + (size_t)i * S_DIM + j] = sg;
    }
}

extern "C" void kernel_launch(void* const* d_in, const int* in_sizes, int n_in,
                              void* d_out, int out_size, void* d_ws, size_t ws_size,
                              hipStream_t stream) {
    const float* feats = (const float*)d_in[0];
    const float* W1 = (const float*)d_in[1];
    const float* b1 = (const float*)d_in[2];
    const float* W2 = (const float*)d_in[3];
    const float* b2 = (const float*)d_in[4];
    const float* W3 = (const float*)d_in[5];
    const float* b3 = (const float*)d_in[6];
    float* out = (float*)d_out;

    const int B = in_sizes[0] / (S_DIM * H_DIM);   // = 2
    const int M = B * S_DIM;                       // 1024

    char* ws = (char*)d_ws;
    _Float16* f16  = (_Float16*)ws;                 // 1 MB
    _Float16* aH   = (_Float16*)(ws + (1 << 20));   // 1 MB
    _Float16* cH   = (_Float16*)(ws + (2 << 20));   // 1 MB
    _Float16* w1L  = (_Float16*)(ws + (3 << 20));   // 1 MB
    _Float16* w2L  = (_Float16*)(ws + (4 << 20));   // 256 KB

    convert_all_kernel<<<832, 256, 0, stream>>>(feats, W1, W2, f16, w1L, w2L);
    prep_mfma_kernel<<<dim3(16, M / 32), 256, 0, stream>>>(f16, w1L, b1, aH, cH);
    pair_kernel<<<dim3(S_DIM / TJ, S_DIM / TI, B), 512, 0, stream>>>(aH, cH, w2L, b2, W3, b3, out);
}

// Round 5
// 241.575 us; speedup vs baseline: 1.1637x; 1.1637x over previous
//
#include <hip/hip_runtime.h>

#define S_DIM 512
#define H_DIM 512
#define NH 256
#define TI 16
#define TJ 8
#define SROW 520   // 512 + 8-half pad: rotates banks per row, legal with per-row DMA base

#define AS1 __attribute__((address_space(1)))
#define AS3 __attribute__((address_space(3)))

typedef _Float16 half8 __attribute__((ext_vector_type(8)));
typedef _Float16 half4 __attribute__((ext_vector_type(4)));
typedef float f32x4 __attribute__((ext_vector_type(4)));
typedef float f32x16 __attribute__((ext_vector_type(16)));

// ---------------- k0: fused converts ----------------
__global__ __launch_bounds__(256) void convert_all_kernel(const float* __restrict__ feats,
        const float* __restrict__ W1, const float* __restrict__ W2,
        _Float16* __restrict__ f16, _Float16* __restrict__ w1L, _Float16* __restrict__ w2L) {
    int blk = blockIdx.x;
    if (blk < 512) {
        int t = blk * 256 + threadIdx.x;
        float4 v = ((const float4*)feats)[t];
        half4 h;
        h.x = (_Float16)v.x; h.y = (_Float16)v.y; h.z = (_Float16)v.z; h.w = (_Float16)v.w;
        ((half4*)f16)[t] = h;
    } else if (blk < 768) {
        int t = (blk - 512) * 256 + threadIdx.x;   // 65536
        int gcb = t >> 10, n = t & 1023;
        const float* src = (n < H_DIM) ? &W1[(size_t)(gcb * 8) * H_DIM + n]
                                       : &W1[(size_t)(H_DIM + gcb * 8) * H_DIM + (n - H_DIM)];
        half8 v;
#pragma unroll
        for (int j = 0; j < 8; j++) v[j] = (_Float16)src[(size_t)j * H_DIM];
        *(half8*)&w1L[((size_t)gcb * 1024 + n) * 8] = v;
    } else {
        int t = (blk - 768) * 256 + threadIdx.x;   // 16384
        int gcb = t >> 8, n = t & 255;
        half8 v;
#pragma unroll
        for (int j = 0; j < 8; j++) v[j] = (_Float16)W2[(size_t)(gcb * 8 + j) * NH + n];
        *(half8*)&w2L[((size_t)gcb * 256 + n) * 8] = v;
    }
}

// ---------------- k1: prep GEMM [1024 x 512] @ [512 x 1024], 32x64 tiles ----------
__global__ __launch_bounds__(256) void prep_mfma_kernel(const _Float16* __restrict__ f16,
        const _Float16* __restrict__ w1L, const float* __restrict__ b1,
        _Float16* __restrict__ aH, _Float16* __restrict__ cH) {
    const int n0 = blockIdx.x * 64, m0 = blockIdx.y * 32;
    const int tid = threadIdx.x, wave = tid >> 6, lane = tid & 63;
    const int quad = lane >> 4, l16 = lane & 15;
    const int mg = wave >> 1, ng = wave & 1;
    const int mrow = m0 + mg * 16 + l16;
    int ncol[2];
#pragma unroll
    for (int nt = 0; nt < 2; nt++) ncol[nt] = n0 + ng * 32 + nt * 16 + l16;
    f32x4 acc[2];
    acc[0] = (f32x4)0.f; acc[1] = (f32x4)0.f;
#pragma unroll
    for (int ks = 0; ks < 16; ks++) {
        int gcb = ks * 4 + quad;
        half8 af = *(const half8*)&f16[(size_t)mrow * H_DIM + gcb * 8];
        half8 bf[2];
#pragma unroll
        for (int nt = 0; nt < 2; nt++)
            bf[nt] = *(const half8*)&w1L[((size_t)gcb * 1024 + ncol[nt]) * 8];
#pragma unroll
        for (int nt = 0; nt < 2; nt++)
            acc[nt] = __builtin_amdgcn_mfma_f32_16x16x32_f16(af, bf[nt], acc[nt], 0, 0, 0);
    }
    const bool first_half = (n0 < H_DIM);
#pragma unroll
    for (int nt = 0; nt < 2; nt++) {
        float bias = first_half ? b1[ncol[nt]] : 0.f;
#pragma unroll
        for (int r = 0; r < 4; r++) {
            int m = m0 + mg * 16 + quad * 4 + r;
            float v = acc[nt][r] + bias;
            if (first_half) aH[(size_t)m * H_DIM + ncol[nt]] = (_Float16)v;
            else            cH[(size_t)m * H_DIM + (ncol[nt] - H_DIM)] = (_Float16)v;
        }
    }
}

// ---------------- k2: pair GEMM, 32x32x16 MFMA ------------------------------------
// grid (64,32,B). block 512 = 8 waves = 4 M-groups x 2 N-groups.
// Wave tile 32 pairs x 128 N (nt=4 tiles of 32N). Block = 128 pairs (16i x 8j) x 256N.
// A-operand layout (32x32x16): A[m=lane&31][k=(lane>>5)*8+j]. C/D: col=lane&31,
// row=(reg&3)+8*(reg>>2)+4*(lane>>5).
__global__ __launch_bounds__(512, 4) void pair_kernel(
        const _Float16* __restrict__ aH, const _Float16* __restrict__ cH,
        const _Float16* __restrict__ w2L,
        const float* __restrict__ b2, const float* __restrict__ W3,
        const float* __restrict__ b3, float* __restrict__ out) {
    const int jt = blockIdx.x, it = blockIdx.y, b = blockIdx.z;
    const int i0 = it * TI, j0 = jt * TJ;

    __shared__ __align__(16) _Float16 sa[TI * SROW];    // 16.25 KB
    __shared__ __align__(16) _Float16 sc[TJ * SROW];    //  8.1 KB
    __shared__ float spart[8 * 1024];                   // 32 KB [(ng*4+mg)][row32][col32 rot]

    const int tid = threadIdx.x;
    const int wave = tid >> 6, lane = tid & 63;
    const int mg = wave >> 1, ng = wave & 1;
    const int nb = ng * 128;
    const int m32 = lane & 31, ch = lane >> 5;

    // ---- stage 16 a-rows + 8 c-rows (row base wave-uniform, pad lives between rows)
#pragma unroll
    for (int rr0 = 0; rr0 < 3; rr0++) {
        int rr = rr0 * 8 + wave;
        if (rr < TI) {
            __builtin_amdgcn_global_load_lds(
                (const AS1 unsigned int*)&aH[((size_t)(b * S_DIM + i0 + rr)) * H_DIM + lane * 8],
                (AS3 unsigned int*)&sa[rr * SROW], 16, 0, 0);
        } else {
            int cr = rr - TI;
            __builtin_amdgcn_global_load_lds(
                (const AS1 unsigned int*)&cH[((size_t)(b * S_DIM + j0 + cr)) * H_DIM + lane * 8],
                (AS3 unsigned int*)&sc[cr * SROW], 16, 0, 0);
        }
    }

    // pair row within wave group = m32 ; global block row = mg*32 + m32
    const int il = mg * 4 + (m32 >> 3);   // a-row 0..15
    const int jl = m32 & 7;               // c-row 0..7
    const _Float16* vaB = &sa[il * SROW + ch * 8];
    const _Float16* vcB = &sc[jl * SROW + ch * 8];

    f32x16 acc[4];
#pragma unroll
    for (int nt = 0; nt < 4; nt++) acc[nt] = (f32x16)0.f;

    // B fragment-major: chunk (kc, n) at (kc*256+n)*8 halves; kc = ks*2 + ch
    const _Float16* bp = &w2L[((size_t)ch * 256 + nb + m32) * 8];
    half8 bnxt[4];
#pragma unroll
    for (int nt = 0; nt < 4; nt++) bnxt[nt] = *(const half8*)&bp[nt * 256];

    __syncthreads();   // sa/sc staged

#pragma unroll
    for (int ks = 0; ks < 32; ks++) {
        half8 bf[4];
#pragma unroll
        for (int nt = 0; nt < 4; nt++) bf[nt] = bnxt[nt];
        if (ks < 31) {
            const _Float16* bn = bp + 4096;   // +2*256*8 halves per ks
#pragma unroll
            for (int nt = 0; nt < 4; nt++) bnxt[nt] = *(const half8*)&bn[nt * 256];
            bp = bn;
        }
        half8 va = *(const half8*)&vaB[ks * 16];
        half8 vc = *(const half8*)&vcB[ks * 16];
        half8 af = __builtin_elementwise_max(va + vc, (half8)(_Float16)0.f);
#pragma unroll
        for (int nt = 0; nt < 4; nt++)
            acc[nt] = __builtin_amdgcn_mfma_f32_32x32x16_f16(af, bf[nt], acc[nt], 0, 0, 0);
    }

    // ---- fused epilogue: relu(acc+b2) . W3, partial over this wave's 128 N ----
    float b2v[4], w3v[4];
#pragma unroll
    for (int nt = 0; nt < 4; nt++) {
        int n = nb + nt * 32 + m32;
        b2v[nt] = b2[n];
        w3v[nt] = W3[n];
    }
    const int region = (ng * 4 + mg) * 1024;
#pragma unroll
    for (int r = 0; r < 16; r++) {
        float s = 0.f;
#pragma unroll
        for (int nt = 0; nt < 4; nt++) {
            float v = acc[nt][r] + b2v[nt];
            v = v > 0.f ? v : 0.f;
            s += v * w3v[nt];
        }
        int row = (r & 3) + 8 * (r >> 2) + 4 * ch;
        spart[region + row * 32 + ((m32 + row) & 31)] = s;   // rotated: conflict-free
    }
    __syncthreads();
    if (tid < 256) {
        const int R = tid >> 1, sub = tid & 1;   // R = block pair row, sub = N-half
        const int mgf = R >> 5, rowf = R & 31;
        const float* base = &spart[(sub * 4 + mgf) * 1024 + rowf * 32];
        float s = 0.f;
#pragma unroll
        for (int k = 0; k < 32; k++) s += base[(k + rowf) & 31];
        s += __shfl_xor(s, 1, 2);
        if (sub == 0) {
            float tot = s + b3[0];
            float sg = 1.f / (1.f + __expf(-tot));
            int i = i0 + (R >> 3), j = j0 + (R & 7);
            out[(size_t)b * S_DIM * S_DIM + (size_t)i * S_DIM + j] = sg;
        }
    }
}

extern "C" void kernel_launch(void* const* d_in, const int* in_sizes, int n_in,
                              void* d_out, int out_size, void* d_ws, size_t ws_size,
                              hipStream_t stream) {
    const float* feats = (const float*)d_in[0];
    const float* W1 = (const float*)d_in[1];
    const float* b1 = (const float*)d_in[2];
    const float* W2 = (const float*)d_in[3];
    const float* b2 = (const float*)d_in[4];
    const float* W3 = (const float*)d_in[5];
    const float* b3 = (const float*)d_in[6];
    float* out = (float*)d_out;

    const int B = in_sizes[0] / (S_DIM * H_DIM);   // = 2
    const int M = B * S_DIM;                       // 1024

    char* ws = (char*)d_ws;
    _Float16* f16  = (_Float16*)ws;                 // 1 MB
    _Float16* aH   = (_Float16*)(ws + (1 << 20));   // 1 MB
    _Float16* cH   = (_Float16*)(ws + (2 << 20));   // 1 MB
    _Float16* w1L  = (_Float16*)(ws + (3 << 20));   // 1 MB
    _Float16* w2L  = (_Float16*)(ws + (4 << 20));   // 256 KB

    convert_all_kernel<<<832, 256, 0, stream>>>(feats, W1, W2, f16, w1L, w2L);
    prep_mfma_kernel<<<dim3(16, M / 32), 256, 0, stream>>>(f16, w1L, b1, aH, cH);
    pair_kernel<<<dim3(S_DIM / TJ, S_DIM / TI, B), 512, 0, stream>>>(aH, cH, w2L, b2, W3, b3, out);
}

// Round 6
// 225.903 us; speedup vs baseline: 1.2444x; 1.0694x over previous
//
#include <hip/hip_runtime.h>

#define S_DIM 512
#define H_DIM 512
#define NH 256
#define TI 16
#define TJ 8
#define SROW 520   // 512 + 8-half pad: rotates banks per row; legal (per-row DMA base)

#define AS1 __attribute__((address_space(1)))
#define AS3 __attribute__((address_space(3)))

typedef _Float16 half8 __attribute__((ext_vector_type(8)));
typedef _Float16 half4 __attribute__((ext_vector_type(4)));
typedef float f32x4 __attribute__((ext_vector_type(4)));
typedef float f32x16 __attribute__((ext_vector_type(16)));

// ---------------- k0: fused converts ----------------
__global__ __launch_bounds__(256) void convert_all_kernel(const float* __restrict__ feats,
        const float* __restrict__ W1, const float* __restrict__ W2,
        _Float16* __restrict__ f16, _Float16* __restrict__ w1L, _Float16* __restrict__ w2L) {
    int blk = blockIdx.x;
    if (blk < 512) {
        int t = blk * 256 + threadIdx.x;
        float4 v = ((const float4*)feats)[t];
        half4 h;
        h.x = (_Float16)v.x; h.y = (_Float16)v.y; h.z = (_Float16)v.z; h.w = (_Float16)v.w;
        ((half4*)f16)[t] = h;
    } else if (blk < 768) {
        int t = (blk - 512) * 256 + threadIdx.x;   // 65536
        int gcb = t >> 10, n = t & 1023;
        const float* src = (n < H_DIM) ? &W1[(size_t)(gcb * 8) * H_DIM + n]
                                       : &W1[(size_t)(H_DIM + gcb * 8) * H_DIM + (n - H_DIM)];
        half8 v;
#pragma unroll
        for (int j = 0; j < 8; j++) v[j] = (_Float16)src[(size_t)j * H_DIM];
        *(half8*)&w1L[((size_t)gcb * 1024 + n) * 8] = v;
    } else {
        int t = (blk - 768) * 256 + threadIdx.x;   // 16384
        int gcb = t >> 8, n = t & 255;
        half8 v;
#pragma unroll
        for (int j = 0; j < 8; j++) v[j] = (_Float16)W2[(size_t)(gcb * 8 + j) * NH + n];
        *(half8*)&w2L[((size_t)gcb * 256 + n) * 8] = v;
    }
}

// ---------------- k1: prep GEMM [1024x512]@[512x1024], 32x32x16 MFMA ---------------
// grid (8, 32), block 256 = 4 waves; wave tile 32M x 32N; full-unroll K for ILP.
__global__ __launch_bounds__(256) void prep_mfma_kernel(const _Float16* __restrict__ f16,
        const _Float16* __restrict__ w1L, const float* __restrict__ b1,
        _Float16* __restrict__ aH, _Float16* __restrict__ cH) {
    const int tid = threadIdx.x, wave = tid >> 6, lane = tid & 63;
    const int m32 = lane & 31, ch = lane >> 5;
    const int m0 = blockIdx.y * 32;
    const int n0w = blockIdx.x * 128 + wave * 32;
    const int n = n0w + m32;

    const _Float16* ap = &f16[(size_t)(m0 + m32) * H_DIM + ch * 8];
    const _Float16* bp = &w1L[((size_t)ch * 1024 + n) * 8];

    f32x16 acc = (f32x16)0.f;
#pragma unroll
    for (int ks = 0; ks < 32; ks++) {
        half8 af = *(const half8*)&ap[ks * 16];
        half8 bf = *(const half8*)&bp[(size_t)ks * 16384];   // kc += 2 per ks
        acc = __builtin_amdgcn_mfma_f32_32x32x16_f16(af, bf, acc, 0, 0, 0);
    }
    const bool first_half = (n0w < H_DIM);
    const float bias = first_half ? b1[n & (H_DIM - 1)] : 0.f;
#pragma unroll
    for (int r = 0; r < 16; r++) {
        int m = m0 + (r & 3) + 8 * (r >> 2) + 4 * ch;
        float v = acc[r] + bias;
        if (first_half) aH[(size_t)m * H_DIM + n] = (_Float16)v;
        else            cH[(size_t)m * H_DIM + (n - H_DIM)] = (_Float16)v;
    }
}

// ---------------- k2: pair GEMM, 32x32x16, mt=2 nt=2, depth-2 B prefetch ----------
// grid (64,32,B). block 512 = 8 waves = 2 mg x 4 ng. Wave = 64 pairs x 64 N.
// Block = 128 pairs (16i x 8j) x 256 N.
__global__ __launch_bounds__(512, 4) void pair_kernel(
        const _Float16* __restrict__ aH, const _Float16* __restrict__ cH,
        const _Float16* __restrict__ w2L,
        const float* __restrict__ b2, const float* __restrict__ W3,
        const float* __restrict__ b3, float* __restrict__ out) {
    const int jt = blockIdx.x, it = blockIdx.y, b = blockIdx.z;
    const int i0 = it * TI, j0 = jt * TJ;

    __shared__ __align__(16) _Float16 sa[TI * SROW];    // 16.25 KB
    __shared__ __align__(16) _Float16 sc[TJ * SROW];    //  8.1 KB
    __shared__ float spart[2 * 64 * 32];                // 16 KB [mg][row64][col32 rot]

    const int tid = threadIdx.x;
    const int wave = tid >> 6, lane = tid & 63;
    const int mg = wave >> 2, ng = wave & 3;
    const int nb = ng * 64;
    const int m32 = lane & 31, ch = lane >> 5;

    // ---- stage 16 a-rows + 8 c-rows (row base wave-uniform; pad between rows) ----
#pragma unroll
    for (int rr0 = 0; rr0 < 3; rr0++) {
        int rr = rr0 * 8 + wave;
        if (rr < TI) {
            __builtin_amdgcn_global_load_lds(
                (const AS1 unsigned int*)&aH[((size_t)(b * S_DIM + i0 + rr)) * H_DIM + lane * 8],
                (AS3 unsigned int*)&sa[rr * SROW], 16, 0, 0);
        } else {
            int cr = rr - TI;
            __builtin_amdgcn_global_load_lds(
                (const AS1 unsigned int*)&cH[((size_t)(b * S_DIM + j0 + cr)) * H_DIM + lane * 8],
                (AS3 unsigned int*)&sc[cr * SROW], 16, 0, 0);
        }
    }

    // pair row r_blk = mg*64 + mt*32 + m32 ; il = r_blk>>3, jl = r_blk&7
    const int il0 = mg * 8 + (m32 >> 3);        // mt=0
    const int il1 = il0 + 4;                    // mt=1
    const int jl = m32 & 7;
    const _Float16* vaB0 = &sa[il0 * SROW + ch * 8];
    const _Float16* vaB1 = &sa[il1 * SROW + ch * 8];
    const _Float16* vcB  = &sc[jl * SROW + ch * 8];

    f32x16 acc[2][2];
#pragma unroll
    for (int mt = 0; mt < 2; mt++)
#pragma unroll
        for (int nt = 0; nt < 2; nt++) acc[mt][nt] = (f32x16)0.f;

    // B fragment-major: chunk (kc, n) at (kc*256+n)*8 halves; kc = ks*2 + ch
    const _Float16* bp = &w2L[((size_t)ch * 256 + nb + m32) * 8];
    half8 buf0[2], buf1[2];
    buf0[0] = *(const half8*)&bp[0];
    buf0[1] = *(const half8*)&bp[256];          // +32 cols
    buf1[0] = *(const half8*)&bp[4096];         // ks=1 (+2 chunks)
    buf1[1] = *(const half8*)&bp[4096 + 256];

    __syncthreads();   // sa/sc staged

#pragma unroll
    for (int ks = 0; ks < 32; ks++) {
        half8 bf0 = (ks & 1) ? buf1[0] : buf0[0];
        half8 bf1 = (ks & 1) ? buf1[1] : buf0[1];
        if (ks < 30) {
            const _Float16* bn = bp + (size_t)(ks + 2) * 4096;
            if (ks & 1) { buf1[0] = *(const half8*)&bn[0]; buf1[1] = *(const half8*)&bn[256]; }
            else        { buf0[0] = *(const half8*)&bn[0]; buf0[1] = *(const half8*)&bn[256]; }
        }
        half8 vc  = *(const half8*)&vcB[ks * 16];
        half8 va0 = *(const half8*)&vaB0[ks * 16];
        half8 va1 = *(const half8*)&vaB1[ks * 16];
        half8 af0 = __builtin_elementwise_max(va0 + vc, (half8)(_Float16)0.f);
        half8 af1 = __builtin_elementwise_max(va1 + vc, (half8)(_Float16)0.f);
        acc[0][0] = __builtin_amdgcn_mfma_f32_32x32x16_f16(af0, bf0, acc[0][0], 0, 0, 0);
        acc[0][1] = __builtin_amdgcn_mfma_f32_32x32x16_f16(af0, bf1, acc[0][1], 0, 0, 0);
        acc[1][0] = __builtin_amdgcn_mfma_f32_32x32x16_f16(af1, bf0, acc[1][0], 0, 0, 0);
        acc[1][1] = __builtin_amdgcn_mfma_f32_32x32x16_f16(af1, bf1, acc[1][1], 0, 0, 0);
    }

    // ---- fused epilogue: relu(acc+b2) . W3 over this wave's 64 N ----
    float b2v[2], w3v[2];
#pragma unroll
    for (int nt = 0; nt < 2; nt++) {
        int n = nb + nt * 32 + m32;
        b2v[nt] = b2[n];
        w3v[nt] = W3[n];
    }
#pragma unroll
    for (int mt = 0; mt < 2; mt++)
#pragma unroll
        for (int r = 0; r < 16; r++) {
            float s = 0.f;
#pragma unroll
            for (int nt = 0; nt < 2; nt++) {
                float v = acc[mt][nt][r] + b2v[nt];
                v = v > 0.f ? v : 0.f;
                s += v * w3v[nt];
            }
            // pre-reduce over 32 cols -> 8 col-groups (stays within ch-half)
            s += __shfl_xor(s, 8);
            s += __shfl_xor(s, 16);
            if (m32 < 8) {
                int row = mt * 32 + (r & 3) + 8 * (r >> 2) + 4 * ch;
                int col = ng * 8 + m32;
                spart[mg * 2048 + row * 32 + ((col + row) & 31)] = s;
            }
        }
    __syncthreads();
    {
        const int R = tid >> 2, sub = tid & 3;   // R = block pair row 0..127
        const int mgf = R >> 6, rowf = R & 63;
        const float* base = &spart[mgf * 2048 + rowf * 32];
        float s = 0.f;
#pragma unroll
        for (int k = 0; k < 8; k++) s += base[(sub * 8 + k + rowf) & 31];
        s += __shfl_xor(s, 1);
        s += __shfl_xor(s, 2);
        if (sub == 0) {
            float tot = s + b3[0];
            float sg = 1.f / (1.f + __expf(-tot));
            int i = i0 + (R >> 3), j = j0 + (R & 7);
            out[(size_t)b * S_DIM * S_DIM + (size_t)i * S_DIM + j] = sg;
        }
    }
}

extern "C" void kernel_launch(void* const* d_in, const int* in_sizes, int n_in,
                              void* d_out, int out_size, void* d_ws, size_t ws_size,
                              hipStream_t stream) {
    const float* feats = (const float*)d_in[0];
    const float* W1 = (const float*)d_in[1];
    const float* b1 = (const float*)d_in[2];
    const float* W2 = (const float*)d_in[3];
    const float* b2 = (const float*)d_in[4];
    const float* W3 = (const float*)d_in[5];
    const float* b3 = (const float*)d_in[6];
    float* out = (float*)d_out;

    const int B = in_sizes[0] / (S_DIM * H_DIM);   // = 2

    char* ws = (char*)d_ws;
    _Float16* f16  = (_Float16*)ws;                 // 1 MB
    _Float16* aH   = (_Float16*)(ws + (1 << 20));   // 1 MB
    _Float16* cH   = (_Float16*)(ws + (2 << 20));   // 1 MB
    _Float16* w1L  = (_Float16*)(ws + (3 << 20));   // 1 MB
    _Float16* w2L  = (_Float16*)(ws + (4 << 20));   // 256 KB

    convert_all_kernel<<<832, 256, 0, stream>>>(feats, W1, W2, f16, w1L, w2L);
    prep_mfma_kernel<<<dim3(8, 32), 256, 0, stream>>>(f16, w1L, b1, aH, cH);
    pair_kernel<<<dim3(S_DIM / TJ, S_DIM / TI, B), 512, 0, stream>>>(aH, cH, w2L, b2, W3, b3, out);
}